// Round 10
// baseline (2360.798 us; speedup 1.0000x reference)
//
#include <hip/hip_runtime.h>
#include <hip/hip_bf16.h>
#include <math.h>

#define NB 4
#define NC 16
#define NN 8192
#define NK 9
#define CANDN 128          /* per-row survivor cap */
#define MR (NN / 4)        /* m-range per wave (4 waves per block) */

typedef short s16x8 __attribute__((ext_vector_type(8)));
typedef float f32x4 __attribute__((ext_vector_type(4)));

// ws layout (bytes)
#define OFF_XS   2097152u
#define OFF_NS   4194304u
#define OFF_NK   4325376u
#define OFF_NBR  4456448u
#define OFF_FLAG 5046272u
#define OFF_CAND 5177344u   /* + 32768*128*2 = 13565952 total (< proven ws) */

// ---------------------------------------------------------------------------
// Kernel 0: xt = transposed f32 (rerank/conv); ns32 = numpy-replica norm
// (squares rounded, sequential adds, no FMA — verified R3); nk = 128+0.5*ns
// (always-positive surrogate offset); xs = bf16 hi/lo split [m][hi*16,lo*16].
// ---------------------------------------------------------------------------
__global__ void prep_kernel(const float* __restrict__ x,
                            float* __restrict__ xt,
                            float* __restrict__ ns32,
                            float* __restrict__ nk,
                            unsigned short* __restrict__ xs) {
    int t = blockIdx.x * 256 + threadIdx.x;   // 0..32767
    int b = t >> 13, m = t & (NN - 1);
    const float* xb = x + (size_t)b * NC * NN;
    float v[NC];
#pragma unroll
    for (int c = 0; c < NC; ++c) v[c] = xb[(size_t)c * NN + m];  // coalesced
    float s = __fmul_rn(v[0], v[0]);
#pragma unroll
    for (int c = 1; c < NC; ++c) s = __fadd_rn(s, __fmul_rn(v[c], v[c]));
    float* o = xt + (size_t)t * NC;
#pragma unroll
    for (int c = 0; c < NC; ++c) o[c] = v[c];
    ns32[t] = s;
    nk[t] = 128.0f + 0.5f * s;
    unsigned short* xo = xs + (size_t)t * 32;
#pragma unroll
    for (int c = 0; c < NC; ++c) {
        __hip_bfloat16 h = __float2bfloat16(v[c]);
        float hf = __bfloat162float(h);
        __hip_bfloat16 l = __float2bfloat16(v[c] - hf);
        xo[c] = *(unsigned short*)&h;
        xo[16 + c] = *(unsigned short*)&l;
    }
}

__device__ __forceinline__ s16x8 negbf(s16x8 v) {   // bf16 sign flip
    s16x8 r;
#pragma unroll
    for (int i = 0; i < 8; ++i) r[i] = (short)(v[i] ^ (short)0x8000);
    return r;
}

__device__ __forceinline__ unsigned binof(float key) {
    float kf = fminf(fmaxf(key - 96.0f, 0.0f), 127.0f);
    return (unsigned)kf;
}

// ---------------------------------------------------------------------------
// Kernel 1: MFMA surrogate keys (geometry + fragments verified in R9) with
// HISTOGRAM SELECTION instead of per-key list maintenance.
//  Pass 1 (first 512 m per wave = 2048-m subset): per-row 128-bin LDS
//   histogram of bin(key); scan -> B[row] = first bin with cum >= 12.
//   Subset 12th >= global 12th, so {key < 97+B} is a safe superset filter;
//   diag is the row minimum so it always survives.
//  Pass 2 (full m): recompute identical keys, one f32 compare per key; hits
//   pushed via LDS atomicAdd into a 128-cap per-row list (set-deterministic;
//   rerank is order-invariant). Overflow or B==127 -> flag -> exact fallback.
// ---------------------------------------------------------------------------
__global__ __launch_bounds__(256, 4) void topk_kernel(
        const unsigned short* __restrict__ xs, const float* __restrict__ nk,
        unsigned short* __restrict__ cand, unsigned* __restrict__ flags) {
    __shared__ __align__(16) unsigned hist[32][128];        // 16 KB
    __shared__ __align__(16) unsigned short list[32][CANDN]; // 8 KB
    __shared__ unsigned cnt[32];
    __shared__ unsigned Bbin[32];
    const int tid = threadIdx.x;
    const int L = tid & 63;
    const int q = tid >> 6;                 // wave id = m-quarter
    const int b = blockIdx.x >> 8;          // batch
    const int n0 = (blockIdx.x & 255) * 32; // block's 32-row group
    const int lrow = L & 15;
    const int lk = L >> 4;                  // 0..3

    {   // LDS init
        unsigned* hp = &hist[0][0];
        for (int i = tid; i < 32 * 128; i += 256) hp[i] = 0u;
        unsigned* lp = (unsigned*)&list[0][0];
        for (int i = tid; i < 32 * CANDN / 2; i += 256) lp[i] = 0xFFFFFFFFu;
        if (tid < 32) { cnt[tid] = 0u; Bbin[tid] = 127u; }
    }
    __syncthreads();

    const char* xsb = (const char*)xs + (size_t)b * NN * 64;
    const char* nkb = (const char*)(nk + (size_t)b * NN);

    // B fragments (negated) for the wave's two 16-row tiles (R9-verified).
    const int khalf = (lk & 1) * 16;
    const int r0 = n0 + lrow, r1 = n0 + 16 + lrow;
    const s16x8 bhi0 = negbf(*(const s16x8*)(xsb + (size_t)r0 * 64 + khalf));
    const s16x8 blo0 = negbf(*(const s16x8*)(xsb + (size_t)r0 * 64 + 32 + khalf));
    const s16x8 bhi1 = negbf(*(const s16x8*)(xsb + (size_t)r1 * 64 + khalf));
    const s16x8 blo1 = negbf(*(const s16x8*)(xsb + (size_t)r1 * 64 + 32 + khalf));

    const int m0 = q * MR;
    const int voffA0 = (m0 + lrow) * 64 + lk * 16;
    const int voffK0 = (m0 + lk * 4) * 4;

    // ---- Pass 1: histogram over the wave's first 512 m's ----
    {
        int vA = voffA0, vK = voffK0;
        for (int t = 0; t < 32; ++t) {
            const s16x8 a = *(const s16x8*)(xsb + vA);
            const f32x4 nkv = *(const f32x4*)(nkb + vK);
            f32x4 acc0 = __builtin_amdgcn_mfma_f32_16x16x32_bf16(a, bhi0, nkv, 0, 0, 0);
            acc0 = __builtin_amdgcn_mfma_f32_16x16x32_bf16(a, blo0, acc0, 0, 0, 0);
            f32x4 acc1 = __builtin_amdgcn_mfma_f32_16x16x32_bf16(a, bhi1, nkv, 0, 0, 0);
            acc1 = __builtin_amdgcn_mfma_f32_16x16x32_bf16(a, blo1, acc1, 0, 0, 0);
#pragma unroll
            for (int r = 0; r < 4; ++r)
                atomicAdd(&hist[lrow][binof(acc0[r])], 1u);
#pragma unroll
            for (int r = 0; r < 4; ++r)
                atomicAdd(&hist[16 + lrow][binof(acc1[r])], 1u);
            vA += 1024;
            vK += 64;
        }
    }
    __syncthreads();
    if (tid < 32) {   // scan: first bin with cum >= 12
        unsigned cum = 0;
        unsigned Bv = 127u;
        for (int j = 0; j < 128; ++j) {
            cum += hist[tid][j];
            if (cum >= 12u) { Bv = (unsigned)j; break; }
        }
        Bbin[tid] = Bv;
    }
    __syncthreads();
    const unsigned B0 = Bbin[lrow], B1 = Bbin[16 + lrow];
    const float thr0f = 97.0f + (float)B0;   // key < thr <=> bin <= B (B<127)
    const float thr1f = 97.0f + (float)B1;

    // ---- Pass 2: full scan, compare-only filter ----
    {
        int vA = voffA0, vK = voffK0;
        for (int t = 0; t < MR / 16; ++t) {
            const s16x8 a = *(const s16x8*)(xsb + vA);
            const f32x4 nkv = *(const f32x4*)(nkb + vK);
            f32x4 acc0 = __builtin_amdgcn_mfma_f32_16x16x32_bf16(a, bhi0, nkv, 0, 0, 0);
            acc0 = __builtin_amdgcn_mfma_f32_16x16x32_bf16(a, blo0, acc0, 0, 0, 0);
            f32x4 acc1 = __builtin_amdgcn_mfma_f32_16x16x32_bf16(a, bhi1, nkv, 0, 0, 0);
            acc1 = __builtin_amdgcn_mfma_f32_16x16x32_bf16(a, blo1, acc1, 0, 0, 0);
            unsigned mask = 0u;
#pragma unroll
            for (int r = 0; r < 4; ++r)
                mask |= (acc0[r] < thr0f) ? (1u << r) : 0u;
#pragma unroll
            for (int r = 0; r < 4; ++r)
                mask |= (acc1[r] < thr1f) ? (1u << (4 + r)) : 0u;
            if (__any(mask != 0u)) {
                while (mask) {
                    const int r = __builtin_ctz(mask);
                    mask &= mask - 1u;
                    const int rowi = lrow + ((r >> 2) << 4);
                    const unsigned m =
                        (unsigned)(m0 + t * 16 + lk * 4 + (r & 3));
                    const unsigned idx = atomicAdd(&cnt[rowi], 1u);
                    if (idx < CANDN)
                        list[rowi][idx] = (unsigned short)m;
                }
            }
            vA += 1024;
            vK += 64;
        }
    }
    __syncthreads();

    // dump survivors + flags
    {
        const int rr = tid >> 3, seg = tid & 7;
        const unsigned grow = (unsigned)(b * NN + n0 + rr);
        const uint4* src =
            (const uint4*)((const char*)&list[0][0] + rr * 256 + seg * 32);
        uint4* dst = (uint4*)((char*)cand + (size_t)grow * 256 + seg * 32);
        dst[0] = src[0];
        dst[1] = src[1];
    }
    if (tid < 32)
        flags[b * NN + n0 + tid] =
            (cnt[tid] > (unsigned)CANDN || Bbin[tid] == 127u) ? 1u : 0u;
}

// ---------------------------------------------------------------------------
// Kernel 2: exact re-rank with the BIT-EXACT numpy-f32 replica distance
// (verified R3): dot = sequential fmaf chain; dist = fl(fl(ns_n+ns_m) -
// fl(2*dot)), max(dist,0); diag k32=0; sentinel m>=NN -> k32=~0. Flagged
// rows (never in practice) fall back to an exact full-N scan.
// ---------------------------------------------------------------------------
__global__ __launch_bounds__(256) void rerank_kernel(
        const float* __restrict__ xt, const float* __restrict__ ns32,
        const unsigned short* __restrict__ cand,
        const unsigned* __restrict__ flags,
        unsigned short* __restrict__ nbr) {
    const int row = blockIdx.x * 256 + threadIdx.x;
    const int b = row >> 13;
    const int n = row & (NN - 1);
    const float* xb = xt + (size_t)b * NN * NC;
    const float* xrow = xb + (size_t)n * NC;
    float xv[NC];
#pragma unroll
    for (int c = 0; c < NC; ++c) xv[c] = xrow[c];
    const float nsn = ns32[row];
    const float* nsb = ns32 + b * NN;

    unsigned long long lst[NK];
#pragma unroll
    for (int i = 0; i < NK; ++i) lst[i] = ~0ULL;

    auto consider = [&](int m, unsigned forced_k32, bool use_forced) {
        const float* col = xb + (size_t)(m & (NN - 1)) * NC;
        float dot = 0.0f;
#pragma unroll
        for (int c = 0; c < NC; ++c)
            dot = fmaf(xv[c], col[c], dot);   // npyv_muladd replica (FMA)
        float dist = __fsub_rn(__fadd_rn(nsn, nsb[m & (NN - 1)]),
                               __fmul_rn(2.0f, dot));
        dist = fmaxf(dist, 0.0f);
        unsigned k32 = (m == n) ? 0u : (__float_as_uint(dist) | 0x80000000u);
        if (use_forced) k32 = forced_k32;
        unsigned long long key = ((unsigned long long)k32 << 32) | (unsigned)m;
        if (key < lst[NK - 1]) {
#pragma unroll
            for (int i = 0; i < NK; ++i) {
                unsigned long long aa = lst[i];
                bool sm = key < aa;
                unsigned long long lo = sm ? key : aa;
                unsigned long long hi = sm ? aa : key;
                lst[i] = lo;
                key = hi;
            }
        }
    };

    if (flags[row] != 0u) {
        for (int m = 0; m < NN; ++m) consider(m, 0u, false);
    } else {
        const unsigned short* cl = cand + (size_t)row * CANDN;
        for (int j = 0; j < CANDN; ++j) {
            const int m = cl[j];
            consider(m, 0xFFFFFFFFu, m >= NN);  // sentinel never selected
        }
    }
    unsigned short* o = nbr + (size_t)row * NK;
#pragma unroll
    for (int k = 0; k < NK; ++k) o[k] = (unsigned short)(lst[k] & 0xFFFFu);
}

// ---------------------------------------------------------------------------
// Kernel 3: conv epilogue. Block-uniform output channel -> scalar W/bias.
// ---------------------------------------------------------------------------
__global__ __launch_bounds__(256) void conv_kernel(
        const float* __restrict__ xt, const unsigned short* __restrict__ nbr,
        const float* __restrict__ W, const float* __restrict__ bias,
        float* __restrict__ out) {
    const int tid = threadIdx.x;
    const int ob = blockIdx.x >> 7;       // 0..15, uniform
    const int rb = blockIdx.x & 127;
    const int row = rb * 256 + tid;
    const int b = rb >> 5;                // uniform
    const int n = row & (NN - 1);
    const float* xb = xt + (size_t)b * NN * NC;
    const float* Wo = W + ob * (NC * NK); // uniform
    const unsigned short* nl = nbr + (size_t)row * NK;

    float acc = bias[ob];
    for (int k = 0; k < NK; ++k) {
        const float* col = xb + (size_t)nl[k] * NC;
        float cv[NC];
#pragma unroll
        for (int c = 0; c < NC; ++c) cv[c] = col[c];
#pragma unroll
        for (int c = 0; c < NC; ++c)
            acc = fmaf(Wo[c * NK + k], cv[c], acc);
    }
    out[(size_t)b * NC * NN + (size_t)ob * NN + n] = acc;
}

extern "C" void kernel_launch(void* const* d_in, const int* in_sizes, int n_in,
                              void* d_out, int out_size, void* d_ws, size_t ws_size,
                              hipStream_t stream) {
    const float* x = (const float*)d_in[0];     // [4][16][8192]
    const float* W = (const float*)d_in[1];     // [16][16][9]
    const float* bias = (const float*)d_in[2];  // [16]
    float* out = (float*)d_out;                 // [4][16][8192]

    char* ws = (char*)d_ws;
    float* xt = (float*)ws;
    unsigned short* xs = (unsigned short*)(ws + OFF_XS);
    float* ns32 = (float*)(ws + OFF_NS);
    float* nk = (float*)(ws + OFF_NK);
    unsigned short* nbr = (unsigned short*)(ws + OFF_NBR);
    unsigned* flags = (unsigned*)(ws + OFF_FLAG);
    unsigned short* cand = (unsigned short*)(ws + OFF_CAND);

    prep_kernel<<<128, 256, 0, stream>>>(x, xt, ns32, nk, xs);
    topk_kernel<<<1024, 256, 0, stream>>>(xs, nk, cand, flags);
    rerank_kernel<<<128, 256, 0, stream>>>(xt, ns32, cand, flags, nbr);
    conv_kernel<<<2048, 256, 0, stream>>>(xt, nbr, W, bias, out);
}

// Round 11
// 253.414 us; speedup vs baseline: 9.3160x; 9.3160x over previous
//
#include <hip/hip_runtime.h>
#include <hip/hip_bf16.h>
#include <math.h>

#define NB 4
#define NC 16
#define NN 8192
#define NK 9
#define CANDN 128          /* per-row survivor cap */
#define MR (NN / 4)        /* m-range per wave (4 waves per block) */

typedef short s16x8 __attribute__((ext_vector_type(8)));
typedef float f32x4 __attribute__((ext_vector_type(4)));

// ws layout (bytes)
#define OFF_XS   2097152u
#define OFF_NS   4194304u
#define OFF_NK   4325376u
#define OFF_NBR  4456448u
#define OFF_FLAG 5046272u
#define OFF_CAND 5177344u   /* + 32768*128*2 = 13565952 total (< proven ws 14.9MB) */

// ---------------------------------------------------------------------------
// Kernel 0: xt = transposed f32 (rerank/conv); ns32 = numpy-replica norm
// (squares rounded, sequential adds, no FMA — verified R3); nk = 128+0.5*ns
// (always-positive surrogate offset); xs = bf16 hi/lo split [m][hi*16,lo*16].
// ---------------------------------------------------------------------------
__global__ void prep_kernel(const float* __restrict__ x,
                            float* __restrict__ xt,
                            float* __restrict__ ns32,
                            float* __restrict__ nk,
                            unsigned short* __restrict__ xs) {
    int t = blockIdx.x * 256 + threadIdx.x;   // 0..32767
    int b = t >> 13, m = t & (NN - 1);
    const float* xb = x + (size_t)b * NC * NN;
    float v[NC];
#pragma unroll
    for (int c = 0; c < NC; ++c) v[c] = xb[(size_t)c * NN + m];  // coalesced
    float s = __fmul_rn(v[0], v[0]);
#pragma unroll
    for (int c = 1; c < NC; ++c) s = __fadd_rn(s, __fmul_rn(v[c], v[c]));
    float* o = xt + (size_t)t * NC;
#pragma unroll
    for (int c = 0; c < NC; ++c) o[c] = v[c];
    ns32[t] = s;
    nk[t] = 128.0f + 0.5f * s;
    unsigned short* xo = xs + (size_t)t * 32;
#pragma unroll
    for (int c = 0; c < NC; ++c) {
        __hip_bfloat16 h = __float2bfloat16(v[c]);
        float hf = __bfloat162float(h);
        __hip_bfloat16 l = __float2bfloat16(v[c] - hf);
        xo[c] = *(unsigned short*)&h;
        xo[16 + c] = *(unsigned short*)&l;
    }
}

__device__ __forceinline__ s16x8 negbf(s16x8 v) {   // bf16 sign flip
    s16x8 r;
#pragma unroll
    for (int i = 0; i < 8; ++i) r[i] = (short)(v[i] ^ (short)0x8000);
    return r;
}

// ---------------------------------------------------------------------------
// Kernel 1: MFMA surrogate keys (geometry verified R9/R10) + histogram select.
// ROW-LOCAL bins: base_n = 256 - nk[n] (== key at dist 0); bin = (key-base)*8
// -> width 0.25 dist units, 128 bins cover dist in [0,32].
//  Pass 1 (HALF subset: t<64 per wave): per-row 128-bin LDS histogram;
//   B = first bin with cum >= 12. Superset proof: >=12 subset keys have
//   bin <= B => >=12 full-set keys have bin <= B => the true 12 smallest
//   keys ALL have bin <= B (monotone).
//  Pass 2 (full scan): accept (key-base)*8 < float(B+1) -- identical
//   sub/mul expression as pass-1 binning, so acceptance is bit-consistent.
//   Hits pushed via LDS atomicAdd into a 128-cap per-row list.
//  flags[row] = cnt, or ~0 (overflow / B==127) -> exact fallback in rerank.
// ---------------------------------------------------------------------------
__global__ __launch_bounds__(256, 4) void topk_kernel(
        const unsigned short* __restrict__ xs, const float* __restrict__ nk,
        unsigned short* __restrict__ cand, unsigned* __restrict__ flags) {
    __shared__ __align__(16) unsigned hist[32][128];         // 16 KB
    __shared__ __align__(16) unsigned short list[32][CANDN]; // 8 KB
    __shared__ unsigned cnt[32];
    __shared__ unsigned Bbin[32];
    const int tid = threadIdx.x;
    const int L = tid & 63;
    const int q = tid >> 6;                 // wave id = m-quarter
    const int b = blockIdx.x >> 8;          // batch
    const int n0 = (blockIdx.x & 255) * 32; // block's 32-row group
    const int lrow = L & 15;
    const int lk = L >> 4;                  // 0..3

    {   // LDS init
        unsigned* hp = &hist[0][0];
        for (int i = tid; i < 32 * 128; i += 256) hp[i] = 0u;
        if (tid < 32) { cnt[tid] = 0u; Bbin[tid] = 127u; }
    }
    __syncthreads();

    const char* xsb = (const char*)xs + (size_t)b * NN * 64;
    const float* nkb = nk + (size_t)b * NN;
    const char* nkc = (const char*)nkb;

    // B fragments (negated) for the wave's two 16-row tiles (R9-verified).
    const int khalf = (lk & 1) * 16;
    const int r0 = n0 + lrow, r1 = n0 + 16 + lrow;
    const s16x8 bhi0 = negbf(*(const s16x8*)(xsb + (size_t)r0 * 64 + khalf));
    const s16x8 blo0 = negbf(*(const s16x8*)(xsb + (size_t)r0 * 64 + 32 + khalf));
    const s16x8 bhi1 = negbf(*(const s16x8*)(xsb + (size_t)r1 * 64 + khalf));
    const s16x8 blo1 = negbf(*(const s16x8*)(xsb + (size_t)r1 * 64 + 32 + khalf));

    const float base0 = 256.0f - nkb[r0];   // key at dist 0 for row r0
    const float base1 = 256.0f - nkb[r1];

    const int m0 = q * MR;
    const int voffA0 = (m0 + lrow) * 64 + lk * 16;
    const int voffK0 = (m0 + lk * 4) * 4;

    // ---- Pass 1: histogram over the wave's first 1024 m's (1/2 subset) ----
    {
        int vA = voffA0, vK = voffK0;
        for (int t = 0; t < 64; ++t) {
            const s16x8 a = *(const s16x8*)(xsb + vA);
            const f32x4 nkv = *(const f32x4*)(nkc + vK);
            f32x4 acc0 = __builtin_amdgcn_mfma_f32_16x16x32_bf16(a, bhi0, nkv, 0, 0, 0);
            acc0 = __builtin_amdgcn_mfma_f32_16x16x32_bf16(a, blo0, acc0, 0, 0, 0);
            f32x4 acc1 = __builtin_amdgcn_mfma_f32_16x16x32_bf16(a, bhi1, nkv, 0, 0, 0);
            acc1 = __builtin_amdgcn_mfma_f32_16x16x32_bf16(a, blo1, acc1, 0, 0, 0);
#pragma unroll
            for (int r = 0; r < 4; ++r) {
                float rr = (acc0[r] - base0) * 8.0f;
                rr = fminf(fmaxf(rr, 0.0f), 127.0f);
                atomicAdd(&hist[lrow][(unsigned)rr], 1u);
            }
#pragma unroll
            for (int r = 0; r < 4; ++r) {
                float rr = (acc1[r] - base1) * 8.0f;
                rr = fminf(fmaxf(rr, 0.0f), 127.0f);
                atomicAdd(&hist[16 + lrow][(unsigned)rr], 1u);
            }
            vA += 1024;
            vK += 64;
        }
    }
    __syncthreads();
    if (tid < 32) {   // scan: first bin (0..126) with cum >= 12
        unsigned cum = 0;
        unsigned Bv = 127u;
        for (int j = 0; j < 127; ++j) {
            cum += hist[tid][j];
            if (cum >= 12u) { Bv = (unsigned)j; break; }
        }
        Bbin[tid] = Bv;
    }
    __syncthreads();
    const unsigned B0 = Bbin[lrow], B1 = Bbin[16 + lrow];
    const float Bf0 = (float)(B0 + 1u);
    const float Bf1 = (float)(B1 + 1u);

    // ---- Pass 2: full scan, compare-only filter ----
    {
        int vA = voffA0, vK = voffK0;
        for (int t = 0; t < MR / 16; ++t) {
            const s16x8 a = *(const s16x8*)(xsb + vA);
            const f32x4 nkv = *(const f32x4*)(nkc + vK);
            f32x4 acc0 = __builtin_amdgcn_mfma_f32_16x16x32_bf16(a, bhi0, nkv, 0, 0, 0);
            acc0 = __builtin_amdgcn_mfma_f32_16x16x32_bf16(a, blo0, acc0, 0, 0, 0);
            f32x4 acc1 = __builtin_amdgcn_mfma_f32_16x16x32_bf16(a, bhi1, nkv, 0, 0, 0);
            acc1 = __builtin_amdgcn_mfma_f32_16x16x32_bf16(a, blo1, acc1, 0, 0, 0);
            unsigned mask = 0u;
#pragma unroll
            for (int r = 0; r < 4; ++r)
                mask |= ((acc0[r] - base0) * 8.0f < Bf0) ? (1u << r) : 0u;
#pragma unroll
            for (int r = 0; r < 4; ++r)
                mask |= ((acc1[r] - base1) * 8.0f < Bf1) ? (1u << (4 + r)) : 0u;
            if (__any(mask != 0u)) {
                while (mask) {
                    const int r = __builtin_ctz(mask);
                    mask &= mask - 1u;
                    const int rowi = lrow + ((r >> 2) << 4);
                    const unsigned m =
                        (unsigned)(m0 + t * 16 + lk * 4 + (r & 3));
                    const unsigned idx = atomicAdd(&cnt[rowi], 1u);
                    if (idx < CANDN)
                        list[rowi][idx] = (unsigned short)m;
                }
            }
            vA += 1024;
            vK += 64;
        }
    }
    __syncthreads();

    // dump survivors (bulk, coalesced) + flags (= cnt, or ~0 -> fallback)
    {
        const int rr = tid >> 3, seg = tid & 7;
        const unsigned grow = (unsigned)(b * NN + n0 + rr);
        const uint4* src =
            (const uint4*)((const char*)&list[0][0] + rr * 256 + seg * 32);
        uint4* dst = (uint4*)((char*)cand + (size_t)grow * 256 + seg * 32);
        dst[0] = src[0];
        dst[1] = src[1];
    }
    if (tid < 32) {
        const bool bad = (cnt[tid] > (unsigned)CANDN) || (Bbin[tid] == 127u);
        flags[b * NN + n0 + tid] = bad ? 0xFFFFFFFFu : cnt[tid];
    }
}

// ---------------------------------------------------------------------------
// Kernel 2: exact re-rank, BIT-EXACT numpy-f32 replica (verified R3):
// dot = sequential fmaf chain; dist = fl(fl(ns_n+ns_m)-fl(2*dot)),
// max(dist,0); diag k32=0; stable (dist,idx) order via packed u64.
// 4 threads per row stride the cnt survivors; sorted-9 each; LDS merge of
// 36 -> exact top-9. Flagged rows (statistically never) split a full exact
// scan 4 ways. Grid 512 blocks (vs R10's 128) fixes the occupancy hole.
// ---------------------------------------------------------------------------
__global__ __launch_bounds__(256) void rerank_kernel(
        const float* __restrict__ xt, const float* __restrict__ ns32,
        const unsigned short* __restrict__ cand,
        const unsigned* __restrict__ flags,
        unsigned short* __restrict__ nbr) {
    __shared__ unsigned long long mk[64][36];
    const int tid = threadIdx.x;
    const int lr = tid >> 2;                 // local row 0..63
    const int j = tid & 3;                   // row-segment thread
    const int row = blockIdx.x * 64 + lr;    // 0..32767
    const int b = row >> 13;                 // uniform (64 | 8192)
    const int n = row & (NN - 1);
    const float* xb = xt + (size_t)b * NN * NC;
    const float* xrow = xb + (size_t)n * NC;
    float xv[NC];
#pragma unroll
    for (int c = 0; c < NC; ++c) xv[c] = xrow[c];
    const float nsn = ns32[row];
    const float* nsb = ns32 + b * NN;

    unsigned long long lst[NK];
#pragma unroll
    for (int i = 0; i < NK; ++i) lst[i] = ~0ULL;

    auto consider = [&](int m) {
        const float* col = xb + (size_t)m * NC;
        float dot = 0.0f;
#pragma unroll
        for (int c = 0; c < NC; ++c)
            dot = fmaf(xv[c], col[c], dot);   // npyv_muladd replica (FMA)
        float dist = __fsub_rn(__fadd_rn(nsn, nsb[m]), __fmul_rn(2.0f, dot));
        dist = fmaxf(dist, 0.0f);
        const unsigned k32 = (m == n) ? 0u
                                      : (__float_as_uint(dist) | 0x80000000u);
        unsigned long long key = ((unsigned long long)k32 << 32) | (unsigned)m;
        if (key < lst[NK - 1]) {
#pragma unroll
            for (int i = 0; i < NK; ++i) {
                unsigned long long aa = lst[i];
                bool sm = key < aa;
                unsigned long long lo = sm ? key : aa;
                unsigned long long hi = sm ? aa : key;
                lst[i] = lo;
                key = hi;
            }
        }
    };

    const unsigned nv = flags[row];
    if (nv == 0xFFFFFFFFu) {                 // exact fallback, 4-way split
        for (int m = j * (NN / 4); m < (j + 1) * (NN / 4); ++m) consider(m);
    } else {
        const unsigned short* cl = cand + (size_t)row * CANDN;
        for (unsigned jj = (unsigned)j; jj < nv; jj += 4) consider(cl[jj]);
    }
#pragma unroll
    for (int i = 0; i < NK; ++i) mk[lr][j * NK + i] = lst[i];
    __syncthreads();
    if (j == 0) {
        unsigned long long fin[NK];
#pragma unroll
        for (int i = 0; i < NK; ++i) fin[i] = ~0ULL;
        for (int s = 0; s < 4 * NK; ++s) {
            unsigned long long key = mk[lr][s];
            if (key < fin[NK - 1]) {
#pragma unroll
                for (int i = 0; i < NK; ++i) {
                    unsigned long long aa = fin[i];
                    bool sm = key < aa;
                    unsigned long long lo = sm ? key : aa;
                    unsigned long long hi = sm ? aa : key;
                    fin[i] = lo;
                    key = hi;
                }
            }
        }
        unsigned short* o = nbr + (size_t)row * NK;
#pragma unroll
        for (int k = 0; k < NK; ++k) o[k] = (unsigned short)(fin[k] & 0xFFFFu);
    }
}

// ---------------------------------------------------------------------------
// Kernel 3: conv epilogue. Block-uniform output channel -> scalar W/bias.
// ---------------------------------------------------------------------------
__global__ __launch_bounds__(256) void conv_kernel(
        const float* __restrict__ xt, const unsigned short* __restrict__ nbr,
        const float* __restrict__ W, const float* __restrict__ bias,
        float* __restrict__ out) {
    const int tid = threadIdx.x;
    const int ob = blockIdx.x >> 7;       // 0..15, uniform
    const int rb = blockIdx.x & 127;
    const int row = rb * 256 + tid;
    const int b = rb >> 5;                // uniform
    const int n = row & (NN - 1);
    const float* xb = xt + (size_t)b * NN * NC;
    const float* Wo = W + ob * (NC * NK); // uniform
    const unsigned short* nl = nbr + (size_t)row * NK;

    float acc = bias[ob];
    for (int k = 0; k < NK; ++k) {
        const float* col = xb + (size_t)nl[k] * NC;
        float cv[NC];
#pragma unroll
        for (int c = 0; c < NC; ++c) cv[c] = col[c];
#pragma unroll
        for (int c = 0; c < NC; ++c)
            acc = fmaf(Wo[c * NK + k], cv[c], acc);
    }
    out[(size_t)b * NC * NN + (size_t)ob * NN + n] = acc;
}

extern "C" void kernel_launch(void* const* d_in, const int* in_sizes, int n_in,
                              void* d_out, int out_size, void* d_ws, size_t ws_size,
                              hipStream_t stream) {
    const float* x = (const float*)d_in[0];     // [4][16][8192]
    const float* W = (const float*)d_in[1];     // [16][16][9]
    const float* bias = (const float*)d_in[2];  // [16]
    float* out = (float*)d_out;                 // [4][16][8192]

    char* ws = (char*)d_ws;
    float* xt = (float*)ws;
    unsigned short* xs = (unsigned short*)(ws + OFF_XS);
    float* ns32 = (float*)(ws + OFF_NS);
    float* nk = (float*)(ws + OFF_NK);
    unsigned short* nbr = (unsigned short*)(ws + OFF_NBR);
    unsigned* flags = (unsigned*)(ws + OFF_FLAG);
    unsigned short* cand = (unsigned short*)(ws + OFF_CAND);

    prep_kernel<<<128, 256, 0, stream>>>(x, xt, ns32, nk, xs);
    topk_kernel<<<1024, 256, 0, stream>>>(xs, nk, cand, flags);
    rerank_kernel<<<512, 256, 0, stream>>>(xt, ns32, cand, flags, nbr);
    conv_kernel<<<2048, 256, 0, stream>>>(xt, nbr, W, bias, out);
}